// Round 1
// baseline (423.505 us; speedup 1.0000x reference)
//
#include <hip/hip_runtime.h>
#include <hip/hip_bf16.h>

#define TT 512
#define II 46
#define HH 64
#define GG 192
#define CC 8
#define RR 8     // rows per block
#define KH 192   // packed K for h-GEMM: [h_hi(64) | h_lo(64) | h_hi(64)] x [Whi | Whi | Wlo]
#define KX 160   // packed K for x-GEMM: [x_hi(48) | x_lo(48) | x_hi(48) | 0(16)] x [Wxhi | Wxhi | Wxlo | 0]

typedef __attribute__((ext_vector_type(8))) short short8;
typedef __attribute__((ext_vector_type(4))) float float4v;

__device__ inline unsigned short f2bf_rne(float f) {
  unsigned u = __float_as_uint(f);
  unsigned r = u + 0x7FFFu + ((u >> 16) & 1u);
  return (unsigned short)(r >> 16);
}
__device__ inline float bf2f(unsigned short s) {
  return __uint_as_float(((unsigned)s) << 16);
}
__device__ inline float fsig(float xv) {
  return __builtin_amdgcn_rcpf(1.f + __expf(-xv));
}
__device__ inline float ftanh(float xv) {
  float ax = fabsf(xv);
  float e = __expf(-2.f * ax);
  float t = (1.f - e) * __builtin_amdgcn_rcpf(1.f + e);
  return (xv < 0.f) ? -t : t;
}

// Pack fp32 weights into bf16 hi/lo MFMA-B-ready rows in workspace.
__global__ void pack_w(const float* __restrict__ w_ih, const float* __restrict__ w_hh,
                       unsigned short* __restrict__ wph, unsigned short* __restrict__ wpx) {
  int idx = blockIdx.x * 256 + threadIdx.x;
  const int NH_ = GG * KH;  // 36864
  if (idx < NH_) {
    int g = idx / KH, k = idx % KH;
    float wv = w_hh[g * HH + (k & 63)];
    unsigned short hi = f2bf_rne(wv);
    wph[idx] = (k < 128) ? hi : f2bf_rne(wv - bf2f(hi));
  } else {
    idx -= NH_;
    if (idx < GG * KX) {
      int g = idx / KX, k = idx % KX;
      unsigned short v = 0;
      if (k < 144) {
        int i = (k < 48) ? k : (k < 96 ? k - 48 : k - 96);
        if (i < II) {
          float wv = w_ih[g * II + i];
          unsigned short hi = f2bf_rne(wv);
          v = (k < 96) ? hi : f2bf_rne(wv - bf2f(hi));
        }
      }
      wpx[idx] = v;
    }
  }
}

__launch_bounds__(256, 1)
__global__ void gru_main(const float* __restrict__ x,
                         const float* __restrict__ b_ih, const float* __restrict__ b_hh,
                         const float* __restrict__ fc_w, const float* __restrict__ fc_b,
                         const unsigned short* __restrict__ wph,
                         const unsigned short* __restrict__ wpx,
                         float* __restrict__ out) {
  __shared__ __align__(16) unsigned short hs[16][136];  // [h_hi(64)|h_lo(64)|pad]
  __shared__ __align__(16) unsigned short xs[16][104];  // [x_hi(48)|x_lo(48)|pad]
  __shared__ float hf[RR][HH + 1];
  __shared__ float fcw[CC * HH];
  __shared__ float fcb[CC];
  __shared__ float lgts[RR][CC];

  const int tau = threadIdx.x;
  const int w   = tau >> 6;
  const int l   = tau & 63;
  const int m16 = l & 15;   // A-frag row / C col (local gate)
  const int kg  = l >> 4;   // k-group 0..3
  const int row0 = blockIdx.x * RR;

  for (int i = tau; i < 16 * 136; i += 256) ((unsigned short*)hs)[i] = 0;
  for (int i = tau; i < 16 * 104; i += 256) ((unsigned short*)xs)[i] = 0;

  // per-lane gate unit (hidden index) and biases
  const int u = 16 * w + m16;
  const float b_r  = b_ih[u] + b_hh[u];
  const float b_z  = b_ih[64 + u] + b_hh[64 + u];
  const float b_nx = b_ih[128 + u];
  const float b_nh = b_hh[128 + u];

  // persistent register B-fragments: 3 gate tiles (r,z,n) x k-steps
  short8 bh[3][6], bx[3][5];
  const int gb0 = 16 * w, gb1 = 64 + 16 * w, gb2 = 128 + 16 * w;
  {
    const int gbs[3] = {gb0, gb1, gb2};
#pragma unroll
    for (int tt = 0; tt < 3; ++tt) {
      const unsigned short* baseh = wph + (size_t)(gbs[tt] + m16) * KH + kg * 8;
#pragma unroll
      for (int s = 0; s < 6; ++s) bh[tt][s] = *(const short8*)(baseh + 32 * s);
      const unsigned short* basex = wpx + (size_t)(gbs[tt] + m16) * KX + kg * 8;
#pragma unroll
      for (int s = 0; s < 5; ++s) bx[tt][s] = *(const short8*)(basex + 32 * s);
    }
  }

  // x staging assignment: elements e=tau and e=tau+256 of the 8x46 slab
  const int r1 = tau / II, i1 = tau % II;
  const bool has2 = (tau + 256) < RR * II;
  const int e2 = tau + 256;
  const int r2 = e2 / II, i2 = e2 % II;
  const float* xp1 = x + ((size_t)(row0 + r1) * TT) * II + i1;
  const float* xp2 = x + ((size_t)(row0 + (has2 ? r2 : r1)) * TT) * II + (has2 ? i2 : i1);
  float xv1 = xp1[0];
  float xv2 = xp2[0];

  float hreg[4] = {0.f, 0.f, 0.f, 0.f};
  const bool writer = (kg < 2);  // owns real rows m<8

  for (int t = 0; t < TT; ++t) {
    // ---- Phase A: stage x(t) and h(t) into LDS ----
    {
      unsigned short hi1 = f2bf_rne(xv1);
      unsigned short lo1 = f2bf_rne(xv1 - bf2f(hi1));
      xs[r1][i1] = hi1;
      xs[r1][48 + i1] = lo1;
      if (has2) {
        unsigned short hi2 = f2bf_rne(xv2);
        unsigned short lo2 = f2bf_rne(xv2 - bf2f(hi2));
        xs[r2][i2] = hi2;
        xs[r2][48 + i2] = lo2;
      }
    }
    if (writer) {
#pragma unroll
      for (int e = 0; e < 4; ++e) {
        int mr = kg * 4 + e;
        unsigned short hi = f2bf_rne(hreg[e]);
        unsigned short lo = f2bf_rne(hreg[e] - bf2f(hi));
        hs[mr][u] = hi;
        hs[mr][64 + u] = lo;
      }
    }
    __syncthreads();

    // prefetch next x (latency hidden under MFMA phase)
    if (t < TT - 1) {
      xv1 = xp1[(size_t)(t + 1) * II];
      if (has2) xv2 = xp2[(size_t)(t + 1) * II];
    }

    // ---- Phase B: A-fragments + MFMA + gates ----
    short8 ah[4], axf[3];
#pragma unroll
    for (int s = 0; s < 4; ++s) ah[s] = *(const short8*)&hs[m16][32 * s + kg * 8];
#pragma unroll
    for (int s = 0; s < 3; ++s) axf[s] = *(const short8*)&xs[m16][32 * s + kg * 8];

    float4v acc_r  = {0.f, 0.f, 0.f, 0.f};
    float4v acc_z  = {0.f, 0.f, 0.f, 0.f};
    float4v acc_nh = {0.f, 0.f, 0.f, 0.f};
    float4v acc_nx = {0.f, 0.f, 0.f, 0.f};
#pragma unroll
    for (int s = 0; s < 6; ++s) {
      short8 a = ah[s < 4 ? s : s - 4];
      acc_r  = __builtin_amdgcn_mfma_f32_16x16x32_bf16(a, bh[0][s], acc_r, 0, 0, 0);
      acc_z  = __builtin_amdgcn_mfma_f32_16x16x32_bf16(a, bh[1][s], acc_z, 0, 0, 0);
      acc_nh = __builtin_amdgcn_mfma_f32_16x16x32_bf16(a, bh[2][s], acc_nh, 0, 0, 0);
    }
#pragma unroll
    for (int s = 0; s < 5; ++s) {
      short8 a = axf[s < 3 ? s : s - 3];
      acc_r  = __builtin_amdgcn_mfma_f32_16x16x32_bf16(a, bx[0][s], acc_r, 0, 0, 0);
      acc_z  = __builtin_amdgcn_mfma_f32_16x16x32_bf16(a, bx[1][s], acc_z, 0, 0, 0);
      acc_nx = __builtin_amdgcn_mfma_f32_16x16x32_bf16(a, bx[2][s], acc_nx, 0, 0, 0);
    }

#pragma unroll
    for (int e = 0; e < 4; ++e) {
      float rg = fsig(acc_r[e] + b_r);
      float zg = fsig(acc_z[e] + b_z);
      float pre = acc_nx[e] + b_nx + rg * (acc_nh[e] + b_nh);
      float ng = ftanh(pre);
      hreg[e] = (1.f - zg) * ng + zg * hreg[e];
    }
    __syncthreads();
  }

  // ---- Epilogue: FC + softmax ----
  if (writer) {
#pragma unroll
    for (int e = 0; e < 4; ++e) hf[kg * 4 + e][u] = hreg[e];
  }
  fcw[tau] = fc_w[tau];
  fcw[tau + 256] = fc_w[tau + 256];
  if (tau < CC) fcb[tau] = fc_b[tau];
  __syncthreads();

  if (tau < RR * CC) {
    int rr = tau >> 3, c = tau & 7;
    float acc = fcb[c];
#pragma unroll
    for (int j = 0; j < HH; ++j) acc += hf[rr][j] * fcw[c * HH + j];
    lgts[rr][c] = acc;
  }
  __syncthreads();
  if (tau < RR * CC) {
    int rr = tau >> 3, c = tau & 7;
    float mx = lgts[rr][0];
#pragma unroll
    for (int j = 1; j < CC; ++j) mx = fmaxf(mx, lgts[rr][j]);
    float ssum = 0.f;
#pragma unroll
    for (int j = 0; j < CC; ++j) ssum += __expf(lgts[rr][j] - mx);
    out[(size_t)(row0 + rr) * CC + c] = __expf(lgts[rr][c] - mx) / ssum;
  }
}

extern "C" void kernel_launch(void* const* d_in, const int* in_sizes, int n_in,
                              void* d_out, int out_size, void* d_ws, size_t ws_size,
                              hipStream_t stream) {
  const float* x    = (const float*)d_in[0];
  const float* w_ih = (const float*)d_in[1];
  const float* w_hh = (const float*)d_in[2];
  const float* b_ih = (const float*)d_in[3];
  const float* b_hh = (const float*)d_in[4];
  const float* fc_w = (const float*)d_in[5];
  const float* fc_b = (const float*)d_in[6];

  unsigned short* wph = (unsigned short*)d_ws;
  unsigned short* wpx = wph + GG * KH;

  pack_w<<<264, 256, 0, stream>>>(w_ih, w_hh, wph, wpx);
  gru_main<<<256, 256, 0, stream>>>(x, b_ih, b_hh, fc_w, fc_b, wph, wpx, (float*)d_out);
}

// Round 2
// 344.961 us; speedup vs baseline: 1.2277x; 1.2277x over previous
//
#include <hip/hip_runtime.h>
#include <hip/hip_bf16.h>

#define TT 512
#define II 46
#define HH 64
#define GG 192
#define CC 8
#define RR 8     // rows per block
#define KH 192   // packed K for h-GEMM: [h_hi(64) | h_lo(64) | h_hi(64)] x [Whi | Whi | Wlo]
#define KX 160   // packed K for x-GEMM: [x_hi(48) | x_lo(48) | x_hi(48) | 0(16)] x [Wxhi | Wxhi | Wxlo | 0]

typedef __attribute__((ext_vector_type(8))) short short8;
typedef __attribute__((ext_vector_type(4))) float float4v;

__device__ inline unsigned short f2bf_rne(float f) {
  unsigned u = __float_as_uint(f);
  unsigned r = u + 0x7FFFu + ((u >> 16) & 1u);
  return (unsigned short)(r >> 16);
}
__device__ inline float bf2f(unsigned short s) {
  return __uint_as_float(((unsigned)s) << 16);
}
__device__ inline float fsigm(float xv) {
  return __builtin_amdgcn_rcpf(1.f + __expf(-xv));
}
// tanh(x) = 1 - 2/(1 + e^{2x}); saturates correctly at +-1, branch-free
__device__ inline float ftanh2(float xv) {
  float e = __expf(2.f * xv);
  float uu = __builtin_amdgcn_rcpf(1.f + e);
  return __builtin_fmaf(-2.f, uu, 1.f);
}

// Pack fp32 weights into bf16 hi/lo MFMA-B-ready rows in workspace.
__global__ void pack_w(const float* __restrict__ w_ih, const float* __restrict__ w_hh,
                       unsigned short* __restrict__ wph, unsigned short* __restrict__ wpx) {
  int idx = blockIdx.x * 256 + threadIdx.x;
  const int NH_ = GG * KH;  // 36864
  if (idx < NH_) {
    int g = idx / KH, k = idx % KH;
    float wv = w_hh[g * HH + (k & 63)];
    unsigned short hi = f2bf_rne(wv);
    wph[idx] = (k < 128) ? hi : f2bf_rne(wv - bf2f(hi));
  } else {
    idx -= NH_;
    if (idx < GG * KX) {
      int g = idx / KX, k = idx % KX;
      unsigned short v = 0;
      if (k < 144) {
        int i = (k < 48) ? k : (k < 96 ? k - 48 : k - 96);
        if (i < II) {
          float wv = w_ih[g * II + i];
          unsigned short hi = f2bf_rne(wv);
          v = (k < 96) ? hi : f2bf_rne(wv - bf2f(hi));
        }
      }
      wpx[idx] = v;
    }
  }
}

// Fragment-order LDS layouts:
//  hsf[buf][s][64][8]: A-frag for h-GEMM; lane l kstep s reads hsf[buf][s][l][0..7]
//    value h[row][unit u]: hi at [u>>5][((u>>3)&3)*16+row][u&7], lo at [(u>>5)+2][same][same]
//  xsf[buf][s][64][8]: A-frag for x-GEMM (s=0..2 cover k 0..95 = [hi48|lo48])
//  gxp[buf][8][193]: f32 gx + biases, rows = batch rows, cols = 192 gates (pad 193)
__launch_bounds__(512, 2)
__global__ void gru_main(const float* __restrict__ x,
                         const float* __restrict__ b_ih, const float* __restrict__ b_hh,
                         const float* __restrict__ fc_w, const float* __restrict__ fc_b,
                         const unsigned short* __restrict__ wph,
                         const unsigned short* __restrict__ wpx,
                         float* __restrict__ out) {
  __shared__ __align__(16) unsigned short hsf[2][4][64][8];
  __shared__ __align__(16) unsigned short xsf[2][3][64][8];
  __shared__ float gxp[2][8][193];
  __shared__ float hf[RR][HH + 1];
  __shared__ float fcw[CC * HH];
  __shared__ float fcbs[CC];
  __shared__ float lgts[RR][CC];

  const int tau = threadIdx.x;
  const int w8  = tau >> 6;   // wave 0..7
  const int l   = tau & 63;
  const int m16 = l & 15;
  const int kg  = l >> 4;
  const int row0 = blockIdx.x * RR;

  {
    unsigned short* hz = &hsf[0][0][0][0];
    for (int i = tau; i < 2 * 4 * 64 * 8; i += 512) hz[i] = 0;
    unsigned short* xz = &xsf[0][0][0][0];
    for (int i = tau; i < 2 * 3 * 64 * 8; i += 512) xz[i] = 0;
    float* gz = &gxp[0][0][0];
    for (int i = tau; i < 2 * 8 * 193; i += 512) gz[i] = 0.f;
  }

  float hreg[4] = {0.f, 0.f, 0.f, 0.f};

  if (w8 < 4) {
    // ================= CONSUMER: h-recurrence =================
    const int u = 16 * w8 + m16;       // gate unit owned by this lane
    const float bnh = b_hh[128 + u];
    short8 bh[3][6];
    {
      const int gbs[3] = {16 * w8, 64 + 16 * w8, 128 + 16 * w8};
#pragma unroll
      for (int tt = 0; tt < 3; ++tt) {
        const unsigned short* bb = wph + (size_t)(gbs[tt] + m16) * KH + kg * 8;
#pragma unroll
        for (int s = 0; s < 6; ++s) bh[tt][s] = *(const short8*)(bb + 32 * s);
      }
    }
    const int sh  = w8 >> 1;                 // hi kstep for unit u
    const int kgr = (2 * w8 + (m16 >> 3)) & 3;
    const int jh  = m16 & 7;
    const int rb2 = (kg & 1) * 4;            // masked (in-bounds) gxp read row base
    const bool wr = (kg < 2);                // this lane owns real rows

    __syncthreads();  // prologue sync #1

    for (int t = 0; t < TT; ++t) {
      __syncthreads();
      const int cur = t & 1, nxt = cur ^ 1;
      short8 a0 = *(const short8*)&hsf[cur][0][l][0];
      short8 a1 = *(const short8*)&hsf[cur][1][l][0];
      short8 a2 = *(const short8*)&hsf[cur][2][l][0];
      short8 a3 = *(const short8*)&hsf[cur][3][l][0];
      float4v accr, accz, accn;
      float gns0, gns1, gns2, gns3;
      accr[0] = gxp[cur][rb2 + 0][u];
      accr[1] = gxp[cur][rb2 + 1][u];
      accr[2] = gxp[cur][rb2 + 2][u];
      accr[3] = gxp[cur][rb2 + 3][u];
      accz[0] = gxp[cur][rb2 + 0][64 + u];
      accz[1] = gxp[cur][rb2 + 1][64 + u];
      accz[2] = gxp[cur][rb2 + 2][64 + u];
      accz[3] = gxp[cur][rb2 + 3][64 + u];
      gns0 = gxp[cur][rb2 + 0][128 + u];
      gns1 = gxp[cur][rb2 + 1][128 + u];
      gns2 = gxp[cur][rb2 + 2][128 + u];
      gns3 = gxp[cur][rb2 + 3][128 + u];
      accn[0] = bnh; accn[1] = bnh; accn[2] = bnh; accn[3] = bnh;

#pragma unroll
      for (int s = 0; s < 6; ++s) {
        short8 a = (s == 0 || s == 4) ? a0 : (s == 1 || s == 5) ? a1 : (s == 2) ? a2 : a3;
        accr = __builtin_amdgcn_mfma_f32_16x16x32_bf16(a, bh[0][s], accr, 0, 0, 0);
        accz = __builtin_amdgcn_mfma_f32_16x16x32_bf16(a, bh[1][s], accz, 0, 0, 0);
        accn = __builtin_amdgcn_mfma_f32_16x16x32_bf16(a, bh[2][s], accn, 0, 0, 0);
      }

      const float gg[4] = {gns0, gns1, gns2, gns3};
#pragma unroll
      for (int e = 0; e < 4; ++e) {
        float r = fsigm(accr[e]);
        float z = fsigm(accz[e]);
        float pre = __builtin_fmaf(r, accn[e], gg[e]);
        float n = ftanh2(pre);
        hreg[e] = n + z * (hreg[e] - n);
        if (wr) {
          unsigned short hi = f2bf_rne(hreg[e]);
          unsigned short lo = f2bf_rne(hreg[e] - bf2f(hi));
          hsf[nxt][sh][kgr * 16 + kg * 4 + e][jh] = hi;
          hsf[nxt][sh + 2][kgr * 16 + kg * 4 + e][jh] = lo;
        }
      }
    }
  } else {
    // ================= PRODUCER: gx(t) = x(t)*W_ih^T + biases =================
    const int wp = w8 - 4;
    const int u = 16 * wp + m16;
    const float br = b_ih[u] + b_hh[u];
    const float bz = b_ih[64 + u] + b_hh[64 + u];
    const float bn = b_ih[128 + u];
    short8 bx[3][5];
    {
      const int gbs[3] = {16 * wp, 64 + 16 * wp, 128 + 16 * wp};
#pragma unroll
      for (int tt = 0; tt < 3; ++tt) {
        const unsigned short* bb = wpx + (size_t)(gbs[tt] + m16) * KX + kg * 8;
#pragma unroll
        for (int s = 0; s < 5; ++s) bx[tt][s] = *(const short8*)(bb + 32 * s);
      }
    }
    const bool wr = (kg < 2);

    // x staging: this thread owns elements p and p+256 of the 8x46 slab
    const int p = tau - 256;
    const int r1 = p / II, i1 = p % II;
    const bool has2 = (p + 256) < RR * II;
    const int e2 = p + 256;
    const int r2g = has2 ? (e2 / II) : r1;
    const int i2g = has2 ? (e2 % II) : i1;
    const float* xp1 = x + (size_t)(row0 + r1) * TT * II + i1;
    const float* xp2 = x + (size_t)(row0 + r2g) * TT * II + i2g;
    const int s1h = i1 >> 5, kg1h = (i1 >> 3) & 3, j1 = i1 & 7;
    const int k1l = 48 + i1;
    const int s1l = k1l >> 5, kg1l = (k1l >> 3) & 3, j1l = k1l & 7;
    const int s2h = i2g >> 5, kg2h = (i2g >> 3) & 3, j2 = i2g & 7;
    const int k2l = 48 + i2g;
    const int s2l = k2l >> 5, kg2l = (k2l >> 3) & 3, j2l = k2l & 7;

    auto stageX = [&](int buf, float va, float vb) {
      unsigned short h1 = f2bf_rne(va);
      xsf[buf][s1h][kg1h * 16 + r1][j1] = h1;
      xsf[buf][s1l][kg1l * 16 + r1][j1l] = f2bf_rne(va - bf2f(h1));
      if (has2) {
        unsigned short h2 = f2bf_rne(vb);
        xsf[buf][s2h][kg2h * 16 + r2g][j2] = h2;
        xsf[buf][s2l][kg2l * 16 + r2g][j2l] = f2bf_rne(vb - bf2f(h2));
      }
    };
    auto produceGx = [&](int buf) {
      short8 a0 = *(const short8*)&xsf[buf][0][l][0];
      short8 a1 = *(const short8*)&xsf[buf][1][l][0];
      short8 a2 = *(const short8*)&xsf[buf][2][l][0];
      float4v ar = {br, br, br, br};
      float4v az = {bz, bz, bz, bz};
      float4v an = {bn, bn, bn, bn};
#pragma unroll
      for (int s = 0; s < 5; ++s) {
        short8 a = (s == 0 || s == 3) ? a0 : (s == 1 || s == 4) ? a1 : a2;
        ar = __builtin_amdgcn_mfma_f32_16x16x32_bf16(a, bx[0][s], ar, 0, 0, 0);
        az = __builtin_amdgcn_mfma_f32_16x16x32_bf16(a, bx[1][s], az, 0, 0, 0);
        an = __builtin_amdgcn_mfma_f32_16x16x32_bf16(a, bx[2][s], an, 0, 0, 0);
      }
      if (wr) {
#pragma unroll
        for (int e = 0; e < 4; ++e) {
          gxp[buf][kg * 4 + e][u] = ar[e];
          gxp[buf][kg * 4 + e][64 + u] = az[e];
          gxp[buf][kg * 4 + e][128 + u] = an[e];
        }
      }
    };

    // prologue: load x(0),x(1),x(2); stage x(0)->xs[0]
    float v0a = xp1[0], v0b = xp2[0];
    float v1a = xp1[II], v1b = xp2[II];
    float xc1 = xp1[2 * II], xc2 = xp2[2 * II];
    stageX(0, v0a, v0b);
    __syncthreads();  // prologue sync #1
    produceGx(0);     // gxp[0] = gx(0)
    stageX(1, v1a, v1b);  // xs[1] = x(1)

    for (int t = 0; t < TT; ++t) {
      __syncthreads();
      // issue next global loads first (drained at next barrier, hidden)
      float nx1 = 0.f, nx2 = 0.f;
      if (t + 3 < TT) {
        nx1 = xp1[(size_t)(t + 3) * II];
        nx2 = xp2[(size_t)(t + 3) * II];
      }
      if (t + 1 < TT) produceGx((t + 1) & 1);   // gxp[(t+1)&1] = gx(t+1) from xs[(t+1)&1]
      if (t + 2 < TT) stageX(t & 1, xc1, xc2);  // xs[t&1] = x(t+2)
      xc1 = nx1; xc2 = nx2;
    }
  }

  // ================= Epilogue: FC + softmax =================
  if (w8 < 4 && kg < 2) {
#pragma unroll
    for (int e = 0; e < 4; ++e) hf[kg * 4 + e][16 * w8 + m16] = hreg[e];
  }
  fcw[tau] = fc_w[tau];  // tau < 512 == CC*HH
  if (tau < CC) fcbs[tau] = fc_b[tau];
  __syncthreads();
  if (tau < RR * CC) {
    int rr = tau >> 3, c = tau & 7;
    float acc = fcbs[c];
#pragma unroll
    for (int j = 0; j < HH; ++j) acc += hf[rr][j] * fcw[c * HH + j];
    lgts[rr][c] = acc;
  }
  __syncthreads();
  if (tau < RR * CC) {
    int rr = tau >> 3, c = tau & 7;
    float mx = lgts[rr][0];
#pragma unroll
    for (int j = 1; j < CC; ++j) mx = fmaxf(mx, lgts[rr][j]);
    float ssum = 0.f;
#pragma unroll
    for (int j = 0; j < CC; ++j) ssum += __expf(lgts[rr][j] - mx);
    out[(size_t)(row0 + rr) * CC + c] = __expf(lgts[rr][c] - mx) / ssum;
  }
}

extern "C" void kernel_launch(void* const* d_in, const int* in_sizes, int n_in,
                              void* d_out, int out_size, void* d_ws, size_t ws_size,
                              hipStream_t stream) {
  const float* x    = (const float*)d_in[0];
  const float* w_ih = (const float*)d_in[1];
  const float* w_hh = (const float*)d_in[2];
  const float* b_ih = (const float*)d_in[3];
  const float* b_hh = (const float*)d_in[4];
  const float* fc_w = (const float*)d_in[5];
  const float* fc_b = (const float*)d_in[6];

  unsigned short* wph = (unsigned short*)d_ws;
  unsigned short* wpx = wph + GG * KH;

  pack_w<<<264, 256, 0, stream>>>(w_ih, w_hh, wph, wpx);
  gru_main<<<256, 512, 0, stream>>>(x, b_ih, b_hh, fc_w, fc_b, wph, wpx, (float*)d_out);
}

// Round 3
// 200.715 us; speedup vs baseline: 2.1100x; 1.7187x over previous
//
#include <hip/hip_runtime.h>
#include <hip/hip_bf16.h>

#define TT 512
#define II 46
#define HH 64
#define GG 192
#define CC 8
#define RR 8     // rows per block

typedef __attribute__((ext_vector_type(8))) _Float16 half8;
typedef __attribute__((ext_vector_type(4))) float float4v;

__device__ inline float fsigm(float xv) {
  return __builtin_amdgcn_rcpf(1.f + __expf(-xv));
}
// tanh(x) = 1 - 2/(1 + e^{2x}); saturates correctly at +-1, branch-free
__device__ inline float ftanh2(float xv) {
  float e = __expf(2.f * xv);
  float uu = __builtin_amdgcn_rcpf(1.f + e);
  return __builtin_fmaf(-2.f, uu, 1.f);
}

// Pack fp32 weights into f16 MFMA-B-ready rows: wph[g][k]=w_hh[g][k] (k<64),
// wpx[g][k]=w_ih[g][k] for k<46 else 0 (K padded to 64).
__global__ void pack_w(const float* __restrict__ w_ih, const float* __restrict__ w_hh,
                       _Float16* __restrict__ wph, _Float16* __restrict__ wpx) {
  int idx = blockIdx.x * 256 + threadIdx.x;  // 24576 total
  if (idx < GG * HH) {
    wph[idx] = (_Float16)w_hh[idx];
  } else {
    idx -= GG * HH;
    if (idx < GG * 64) {
      int g = idx >> 6, k = idx & 63;
      wpx[idx] = (_Float16)(k < II ? w_ih[g * II + k] : 0.f);
    }
  }
}

// LDS layouts (fragment-order, f16):
//  hsf[buf][s][64][8]: A-frag for h-GEMM; lane l kstep s reads hsf[buf][s][l][0..7]
//    element h[row][unit k]: s=k>>5, kgrp=(k>>3)&3, j=k&7, line=kgrp*16+row
//  xsf[buf][s][64][8]: same for x (k<46 real, rest zero)
//  gxpT[buf][gate][unit 64][row pad 12] f32: gx*W_ih^T + biases, transposed
__launch_bounds__(512, 2)
__global__ void gru_main(const float* __restrict__ x,
                         const float* __restrict__ b_ih, const float* __restrict__ b_hh,
                         const float* __restrict__ fc_w, const float* __restrict__ fc_b,
                         const _Float16* __restrict__ wph,
                         const _Float16* __restrict__ wpx,
                         float* __restrict__ out) {
  __shared__ __align__(16) _Float16 hsf[2][2][64][8];
  __shared__ __align__(16) _Float16 xsf[2][2][64][8];
  __shared__ __align__(16) float gxpT[2][3][64][12];
  __shared__ float hf[RR][HH + 1];
  __shared__ float fcw[CC * HH];
  __shared__ float fcbs[CC];
  __shared__ float lgts[RR][CC];

  const int tau = threadIdx.x;
  const int w8  = tau >> 6;   // wave 0..7
  const int l   = tau & 63;
  const int m16 = l & 15;
  const int kg  = l >> 4;
  const int row0 = blockIdx.x * RR;

  {
    _Float16* hz = &hsf[0][0][0][0];
    for (int i = tau; i < 2 * 2 * 64 * 8; i += 512) hz[i] = (_Float16)0.f;
    _Float16* xz = &xsf[0][0][0][0];
    for (int i = tau; i < 2 * 2 * 64 * 8; i += 512) xz[i] = (_Float16)0.f;
  }
  __syncthreads();  // init fence (fixes zero-init vs stage race)

  float hreg[2] = {0.f, 0.f};
  // final-owner rows for this lane after the e=2,3 shuffle:
  const int row0l = (kg & 1) * 4 + ((kg >> 1) & 1) * 2;

  if (w8 < 4) {
    // ================= CONSUMER: h-recurrence =================
    const int u = 16 * w8 + m16;       // gate unit owned by this lane
    const float bnh = b_hh[128 + u];
    half8 bh[3][2];
    {
      const int gbs[3] = {16 * w8, 64 + 16 * w8, 128 + 16 * w8};
#pragma unroll
      for (int tt = 0; tt < 3; ++tt) {
        const _Float16* bb = wph + (size_t)(gbs[tt] + m16) * 64 + kg * 8;
        bh[tt][0] = *(const half8*)(bb);
        bh[tt][1] = *(const half8*)(bb + 32);
      }
    }
    // h-write target for unit u, rows row0l+i
    const int sh  = w8 >> 1;
    const int kgp = (u >> 3) & 3;
    const int jp  = u & 7;
    const bool lo2 = (kg < 2);

    __syncthreads();  // prologue sync
    __builtin_amdgcn_s_setprio(1);

    for (int t = 0; t < TT; ++t) {
      __syncthreads();
      const int cur = t & 1, nxt = cur ^ 1;
      half8 a0 = *(const half8*)&hsf[cur][0][l][0];
      half8 a1 = *(const half8*)&hsf[cur][1][l][0];
      // owner-layout gx reads: issued early, consumed after MFMA+shuffle
      float2 gR = *(const float2*)&gxpT[cur][0][u][row0l];
      float2 gZ = *(const float2*)&gxpT[cur][1][u][row0l];
      float2 gN = *(const float2*)&gxpT[cur][2][u][row0l];

      float4v accr = {0.f, 0.f, 0.f, 0.f};
      float4v accz = {0.f, 0.f, 0.f, 0.f};
      float4v accn = {bnh, bnh, bnh, bnh};
      accr = __builtin_amdgcn_mfma_f32_16x16x32_f16(a0, bh[0][0], accr, 0, 0, 0);
      accz = __builtin_amdgcn_mfma_f32_16x16x32_f16(a0, bh[1][0], accz, 0, 0, 0);
      accn = __builtin_amdgcn_mfma_f32_16x16x32_f16(a0, bh[2][0], accn, 0, 0, 0);
      accr = __builtin_amdgcn_mfma_f32_16x16x32_f16(a1, bh[0][1], accr, 0, 0, 0);
      accz = __builtin_amdgcn_mfma_f32_16x16x32_f16(a1, bh[1][1], accz, 0, 0, 0);
      accn = __builtin_amdgcn_mfma_f32_16x16x32_f16(a1, bh[2][1], accn, 0, 0, 0);

      // redistribute rows 2,3 (mod 4) to the kg>=2 lanes: every lane then
      // owns 2 real gate-sets instead of 32 lanes owning 4.
      float r2 = __shfl_xor(accr[2], 32), r3 = __shfl_xor(accr[3], 32);
      float z2 = __shfl_xor(accz[2], 32), z3 = __shfl_xor(accz[3], 32);
      float n2 = __shfl_xor(accn[2], 32), n3 = __shfl_xor(accn[3], 32);
      float aR[2] = {lo2 ? accr[0] : r2, lo2 ? accr[1] : r3};
      float aZ[2] = {lo2 ? accz[0] : z2, lo2 ? accz[1] : z3};
      float aN[2] = {lo2 ? accn[0] : n2, lo2 ? accn[1] : n3};
      float gr[2] = {gR.x, gR.y}, gz[2] = {gZ.x, gZ.y}, gn[2] = {gN.x, gN.y};

#pragma unroll
      for (int i = 0; i < 2; ++i) {
        float rg = fsigm(aR[i] + gr[i]);
        float zg = fsigm(aZ[i] + gz[i]);
        float pre = __builtin_fmaf(rg, aN[i], gn[i]);
        float ng = ftanh2(pre);
        hreg[i] = ng + zg * (hreg[i] - ng);
        hsf[nxt][sh][kgp * 16 + row0l + i][jp] = (_Float16)hreg[i];
      }
    }
    __builtin_amdgcn_s_setprio(0);
  } else {
    // ================= PRODUCER: gxpT(t) = x(t)*W_ih^T + biases =================
    const int wp = w8 - 4;
    const int u = 16 * wp + m16;
    const float br = b_ih[u] + b_hh[u];
    const float bz = b_ih[64 + u] + b_hh[64 + u];
    const float bn = b_ih[128 + u];
    half8 bx[3][2];
    {
      const int gbs[3] = {16 * wp, 64 + 16 * wp, 128 + 16 * wp};
#pragma unroll
      for (int tt = 0; tt < 3; ++tt) {
        const _Float16* bb = wpx + (size_t)(gbs[tt] + m16) * 64 + kg * 8;
        bx[tt][0] = *(const half8*)(bb);
        bx[tt][1] = *(const half8*)(bb + 32);
      }
    }
    const bool wr = (kg < 2);

    // x staging: this thread owns elements p and p+256 of the 8x46 slab
    const int p = tau - 256;
    const int r1 = p / II, i1 = p % II;
    const bool has2 = (p + 256) < RR * II;
    const int e2 = p + 256;
    const int r2g = has2 ? (e2 / II) : r1;
    const int i2g = has2 ? (e2 % II) : i1;
    const float* xp1 = x + (size_t)(row0 + r1) * TT * II + i1;
    const float* xp2 = x + (size_t)(row0 + r2g) * TT * II + i2g;
    const int s1 = i1 >> 5, kg1 = (i1 >> 3) & 3, j1 = i1 & 7;
    const int s2 = i2g >> 5, kg2 = (i2g >> 3) & 3, j2 = i2g & 7;

    auto stageX = [&](int buf, float va, float vb) {
      xsf[buf][s1][kg1 * 16 + r1][j1] = (_Float16)va;
      if (has2) xsf[buf][s2][kg2 * 16 + r2g][j2] = (_Float16)vb;
    };
    auto produceGx = [&](int buf) {
      half8 a0 = *(const half8*)&xsf[buf][0][l][0];
      half8 a1 = *(const half8*)&xsf[buf][1][l][0];
      float4v ar = {br, br, br, br};
      float4v az = {bz, bz, bz, bz};
      float4v an = {bn, bn, bn, bn};
      ar = __builtin_amdgcn_mfma_f32_16x16x32_f16(a0, bx[0][0], ar, 0, 0, 0);
      az = __builtin_amdgcn_mfma_f32_16x16x32_f16(a0, bx[1][0], az, 0, 0, 0);
      an = __builtin_amdgcn_mfma_f32_16x16x32_f16(a0, bx[2][0], an, 0, 0, 0);
      ar = __builtin_amdgcn_mfma_f32_16x16x32_f16(a1, bx[0][1], ar, 0, 0, 0);
      az = __builtin_amdgcn_mfma_f32_16x16x32_f16(a1, bx[1][1], az, 0, 0, 0);
      an = __builtin_amdgcn_mfma_f32_16x16x32_f16(a1, bx[2][1], an, 0, 0, 0);
      if (wr) {
        *(float4v*)&gxpT[buf][0][u][kg * 4] = ar;
        *(float4v*)&gxpT[buf][1][u][kg * 4] = az;
        *(float4v*)&gxpT[buf][2][u][kg * 4] = an;
      }
    };

    // prologue: load x(0),x(1),x(2); stage x(0); produce gx(0); stage x(1)
    float v0a = xp1[0], v0b = xp2[0];
    float v1a = xp1[II], v1b = xp2[II];
    float xc1 = xp1[2 * II], xc2 = xp2[2 * II];
    stageX(0, v0a, v0b);
    __syncthreads();  // prologue sync
    produceGx(0);
    stageX(1, v1a, v1b);

    for (int t = 0; t < TT; ++t) {
      __syncthreads();
      float nx1 = 0.f, nx2 = 0.f;
      if (t + 3 < TT) {
        nx1 = xp1[(size_t)(t + 3) * II];
        nx2 = xp2[(size_t)(t + 3) * II];
      }
      if (t + 1 < TT) produceGx((t + 1) & 1);   // gx(t+1) from xsf[(t+1)&1]
      if (t + 2 < TT) stageX(t & 1, xc1, xc2);  // xsf[t&1] = x(t+2)
      xc1 = nx1; xc2 = nx2;
    }
  }

  // ================= Epilogue: FC + softmax =================
  if (w8 < 4) {
    hf[row0l + 0][16 * w8 + m16] = hreg[0];
    hf[row0l + 1][16 * w8 + m16] = hreg[1];
  }
  fcw[tau] = fc_w[tau];  // tau < 512 == CC*HH
  if (tau < CC) fcbs[tau] = fc_b[tau];
  __syncthreads();
  if (tau < RR * CC) {
    int rr = tau >> 3, c = tau & 7;
    float acc = fcbs[c];
#pragma unroll
    for (int j = 0; j < HH; ++j) acc += hf[rr][j] * fcw[c * HH + j];
    lgts[rr][c] = acc;
  }
  __syncthreads();
  if (tau < RR * CC) {
    int rr = tau >> 3, c = tau & 7;
    float mx = lgts[rr][0];
#pragma unroll
    for (int j = 1; j < CC; ++j) mx = fmaxf(mx, lgts[rr][j]);
    float ssum = 0.f;
#pragma unroll
    for (int j = 0; j < CC; ++j) ssum += __expf(lgts[rr][j] - mx);
    out[(size_t)(row0 + rr) * CC + c] = __expf(lgts[rr][c] - mx) / ssum;
  }
}

extern "C" void kernel_launch(void* const* d_in, const int* in_sizes, int n_in,
                              void* d_out, int out_size, void* d_ws, size_t ws_size,
                              hipStream_t stream) {
  const float* x    = (const float*)d_in[0];
  const float* w_ih = (const float*)d_in[1];
  const float* w_hh = (const float*)d_in[2];
  const float* b_ih = (const float*)d_in[3];
  const float* b_hh = (const float*)d_in[4];
  const float* fc_w = (const float*)d_in[5];
  const float* fc_b = (const float*)d_in[6];

  _Float16* wph = (_Float16*)d_ws;
  _Float16* wpx = wph + GG * HH;

  pack_w<<<96, 256, 0, stream>>>(w_ih, w_hh, wph, wpx);
  gru_main<<<256, 512, 0, stream>>>(x, b_ih, b_hh, fc_w, fc_b, wph, wpx, (float*)d_out);
}